// Round 2
// baseline (2373.677 us; speedup 1.0000x reference)
//
#include <hip/hip_runtime.h>
#include <cstdint>
#include <cmath>
#include <cstring>
#include <mutex>

// ============================================================================
// Host-side replication of numpy default_rng(42) -> CG coefficient table.
// Chain: SeedSequence(42) -> PCG64 (128-bit LCG + XSL-RR) -> uniforms
// ((next>>11)*2^-53) and ziggurat standard normals (256-layer, 52-bit).
// R1 fix: SeedSequence mix() is MULT_L*x - MULT_R*y (subtraction), not xor.
// ============================================================================
namespace nprng {

typedef unsigned __int128 u128;

struct PCG64 {
  u128 state, inc;
  static inline u128 mult() {
    return ((u128)0x2360ED051FC65DA4ULL << 64) | 0x4385DF649FCCF645ULL;
  }
  inline void step() { state = state * mult() + inc; }
  inline uint64_t next() {
    step();
    uint64_t hi = (uint64_t)(state >> 64), lo = (uint64_t)state;
    uint64_t x = hi ^ lo;
    unsigned rot = (unsigned)(state >> 122);
    return (x >> rot) | (x << ((64u - rot) & 63u));
  }
  void srandom(u128 initstate, u128 initseq) {
    state = 0;
    inc = (initseq << 1) | 1;
    step();
    state += initstate;
    step();
  }
};

// numpy SeedSequence(42): pool mixing per bit_generator.pyx constants.
static void seed_sequence_42_raw(uint32_t st[8]) {
  uint32_t pool[4];
  uint32_t hash_const = 0x43b0d7e5u;  // INIT_A
  auto hashmix = [&hash_const](uint32_t v) -> uint32_t {
    v ^= hash_const;
    hash_const *= 0x931e8875u;  // MULT_A
    v *= hash_const;
    v ^= v >> 16;
    return v;
  };
  auto mix = [](uint32_t x, uint32_t y) -> uint32_t {
    // result = MIX_MULT_L*x - MIX_MULT_R*y; result ^= result >> 16
    uint32_t r = 0xca01f9ddu * x - 0x4973f715u * y;
    r ^= r >> 16;
    return r;
  };
  pool[0] = hashmix(42u);
  for (int i = 1; i < 4; ++i) pool[i] = hashmix(0u);
  for (int s = 0; s < 4; ++s)
    for (int d = 0; d < 4; ++d)
      if (s != d) pool[d] = mix(pool[d], hashmix(pool[s]));
  uint32_t gen_const = 0x8b51f9ddu;  // INIT_B
  for (int i = 0; i < 8; ++i) {
    uint32_t v = pool[i & 3];
    v ^= gen_const;
    gen_const *= 0x58f38dedu;  // MULT_B
    v *= gen_const;
    v ^= v >> 16;
    st[i] = v;
  }
}

static inline double next_uniform(PCG64& g) {
  return (double)(g.next() >> 11) * (1.0 / 9007199254740992.0);
}

// Build generator; self-verify against the published first draw of
// default_rng(42).random() == 0.7739560485559633 trying 4 word-order
// conventions (guards against seeding-convention mistakes).
static void make_gen(PCG64& g) {
  uint32_t st[8];
  seed_sequence_42_raw(st);
  const double target = 0.7739560485559633;
  for (int pairing = 0; pairing < 2; ++pairing) {
    uint64_t s[4];
    for (int i = 0; i < 4; ++i)
      s[i] = pairing == 0
                 ? ((uint64_t)st[2 * i] | ((uint64_t)st[2 * i + 1] << 32))
                 : (((uint64_t)st[2 * i] << 32) | (uint64_t)st[2 * i + 1]);
    for (int so = 0; so < 2; ++so) {
      PCG64 t;
      if (so == 0)
        t.srandom(((u128)s[0] << 64) | s[1], ((u128)s[2] << 64) | s[3]);
      else
        t.srandom(((u128)s[1] << 64) | s[0], ((u128)s[3] << 64) | s[2]);
      PCG64 probe = t;
      if (fabs(next_uniform(probe) - target) < 1e-13) {
        g = t;
        return;
      }
    }
  }
  // Fallback: canonical convention (little-endian pairing, seed[0]=high).
  uint64_t s[4];
  for (int i = 0; i < 4; ++i)
    s[i] = (uint64_t)st[2 * i] | ((uint64_t)st[2 * i + 1] << 32);
  g.srandom(((u128)s[0] << 64) | s[1], ((u128)s[2] << 64) | s[3]);
}

struct Zig {
  double wi[256], fi[256];
  uint64_t ki[256];
};

// 256-layer normal ziggurat tables (numpy layout: idx 0 = base+tail layer,
// x_i increasing with i, x_255 = r). Built in long double; value accuracy
// needed is only float32-level, decision boundaries are 1e-13-insensitive.
static void build_zig(Zig& z) {
  const long double R = 3.6541528853610087963519472518L;
  const long double T52 = 4503599627370496.0L;  // 2^52
  long double f255 = expl(-0.5L * R * R);
  long double v =
      R * f255 +
      sqrtl(1.57079632679489661923132169163975144L) *  // sqrt(pi/2)
          erfcl(R / 1.41421356237309504880168872420969808L);
  long double x[256], fi[256];
  x[255] = R;
  fi[255] = f255;
  for (int i = 254; i >= 1; --i) {
    fi[i] = fi[i + 1] + v / x[i + 1];
    long double t = -2.0L * logl(fi[i]);
    x[i] = t > 0 ? sqrtl(t) : 0.0L;
  }
  x[0] = 0.0L;
  fi[0] = 1.0L;
  z.wi[0] = (double)(v / f255 / T52);
  z.fi[0] = 1.0;
  z.ki[0] = (uint64_t)((R * f255 / v) * T52);
  z.ki[1] = 0;
  for (int i = 1; i < 256; ++i) {
    z.wi[i] = (double)(x[i] / T52);
    z.fi[i] = (double)fi[i];
  }
  for (int i = 2; i < 256; ++i)
    z.ki[i] = (uint64_t)((x[i - 1] / x[i]) * T52);
}

// numpy random_standard_normal (ziggurat), incl. GH13361 log1p tail.
static double next_normal(PCG64& g, const Zig& z) {
  const double ZR = 3.6541528853610087963519472518;
  const double ZIR = 0.27366123732975827203338247596;
  for (;;) {
    uint64_t r = g.next();
    int idx = (int)(r & 0xff);
    r >>= 8;
    int sign = (int)(r & 1);
    uint64_t rabs = (r >> 1) & 0x000fffffffffffffULL;
    double x = (double)rabs * z.wi[idx];
    if (sign) x = -x;
    if (rabs < z.ki[idx]) return x;
    if (idx == 0) {
      double xx, yy;
      do {
        xx = -ZIR * log1p(-next_uniform(g));
        yy = -log1p(-next_uniform(g));
      } while (yy + yy <= xx * xx);
      return ((rabs >> 8) & 1) ? -(ZR + xx) : (ZR + xx);
    } else {
      if ((z.fi[idx - 1] - z.fi[idx]) * next_uniform(g) + z.fi[idx] <
          exp(-0.5 * x * x))
        return x;
    }
  }
}

static const int kInstr[15][3] = {{0, 0, 0}, {0, 1, 1}, {0, 2, 2}, {1, 0, 1},
                                 {1, 1, 0}, {1, 1, 1}, {1, 1, 2}, {1, 2, 1},
                                 {1, 2, 2}, {2, 0, 2}, {2, 1, 1}, {2, 1, 2},
                                 {2, 2, 0}, {2, 2, 1}, {2, 2, 2}};
static const int kCOff[15] = {0,   1,   10,  35,  44,  53,  80, 125,
                              170, 245, 270, 315, 390, 415, 490};
// total coeff count = 615

static void build_coeff(float* coeff) {
  Zig z;
  build_zig(z);

  // Secondary self-check: first standard_normal of default_rng(42) is
  // 0.30471707975443135 (numpy docs). Validates the ziggurat path.
  {
    PCG64 probe;
    make_gen(probe);
    (void)next_normal(probe, z);  // value check below is advisory only
  }

  PCG64 g;
  make_gen(g);
  {
    PCG64 probe = g;
    double n0 = next_normal(probe, z);
    (void)n0;  // expected ~0.30471707975443135; no hard assert (no I/O here)
  }

  for (int t = 0; t < 15; ++t) {
    int d1 = 2 * kInstr[t][0] + 1;
    int d2 = 2 * kInstr[t][1] + 1;
    int d3 = 2 * kInstr[t][2] + 1;
    int n = d1 * d2 * d3;
    bool mask[125];
    bool any = false;
    for (int i = 0; i < n; ++i) {
      mask[i] = next_uniform(g) < 0.3;
      any |= mask[i];
    }
    if (!any) mask[0] = true;
    float pw = (float)(1.0 / sqrt((double)(d1 * d2)));
    for (int i = 0; i < n; ++i) {
      float v = (float)next_normal(g, z);
      coeff[kCOff[t] + i] = mask[i] ? v * pw : 0.0f;
    }
  }
}

}  // namespace nprng

// ============================================================================
// Device kernel: 1 thread per (edge, u). Dense 615-MAC contraction with
// wave-uniform CG coeffs (s_load), 51 accumulators, atomicAdd scatter to dst.
// out[node][ 32*cumd3[idx] + u*d3 + k ], OUT_DIM = 1632.
// ============================================================================

template <int D1, int D2, int D3, int COFF, int AOFF>
__device__ __forceinline__ void contract(const float* __restrict__ ct,
                                         const float (&a)[D1],
                                         const float (&b)[D2],
                                         float (&acc)[51]) {
#pragma unroll
  for (int i = 0; i < D1; ++i)
#pragma unroll
    for (int j = 0; j < D2; ++j) {
      float ab = a[i] * b[j];
#pragma unroll
      for (int k = 0; k < D3; ++k)
        acc[AOFF + k] = fmaf(ab, ct[COFF + (i * D2 + j) * D3 + k], acc[AOFF + k]);
    }
}

// X(idx, l1, l2, l3, coeff_off, acc_off)   (out_off = 32*acc_off)
#define FOR_ALL_INSTR(X)                                                   \
  X(0, 0, 0, 0, 0, 0)                                                      \
  X(1, 0, 1, 1, 1, 1)                                                      \
  X(2, 0, 2, 2, 10, 4)                                                     \
  X(3, 1, 0, 1, 35, 9)                                                     \
  X(4, 1, 1, 0, 44, 12)                                                    \
  X(5, 1, 1, 1, 53, 13)                                                    \
  X(6, 1, 1, 2, 80, 16)                                                    \
  X(7, 1, 2, 1, 125, 21)                                                   \
  X(8, 1, 2, 2, 170, 24)                                                   \
  X(9, 2, 0, 2, 245, 29)                                                   \
  X(10, 2, 1, 1, 270, 34)                                                  \
  X(11, 2, 1, 2, 315, 37)                                                  \
  X(12, 2, 2, 0, 390, 42)                                                  \
  X(13, 2, 2, 1, 415, 43)                                                  \
  X(14, 2, 2, 2, 490, 46)

#define DO_CONTRACT(idx, l1, l2, l3, coff, aoff) \
  contract<2 * (l1) + 1, 2 * (l2) + 1, 2 * (l3) + 1, coff, aoff>(ct, aa##l1, bb##l2, acc);

#define DO_EPI(idx, l1, l2, l3, coff, aoff)                                 \
  {                                                                         \
    float wv = W[(idx) * 32];                                               \
    _Pragma("unroll") for (int k = 0; k < 2 * (l3) + 1; ++k)                \
        atomicAdd(O + ((aoff) * 32 + u * (2 * (l3) + 1) + k),               \
                  acc[(aoff) + k] * wv);                                    \
  }

__global__ __launch_bounds__(256) void tp_kernel(
    const float* __restrict__ in1, const float* __restrict__ in2,
    const float* __restrict__ weight, const int* __restrict__ esrc,
    const int* __restrict__ edst, const float* __restrict__ ct,
    float* __restrict__ out, int E) {
  int t = blockIdx.x * blockDim.x + threadIdx.x;
  int e = t >> 5;
  if (e >= E) return;
  int u = t & 31;
  int s = esrc[e];
  int d = edst[e];
  const float* __restrict__ A = in1 + (size_t)s * 288;
  const float* __restrict__ B = in2 + (size_t)e * 9;
  const float* __restrict__ W = weight + (size_t)e * 480 + u;
  float* __restrict__ O = out + (size_t)d * 1632;

  float aa0[1], aa1[3], aa2[5], bb0[1], bb1[3], bb2[5];
  aa0[0] = A[u];
#pragma unroll
  for (int i = 0; i < 3; ++i) aa1[i] = A[32 + u * 3 + i];
#pragma unroll
  for (int i = 0; i < 5; ++i) aa2[i] = A[128 + u * 5 + i];
  bb0[0] = B[0];
#pragma unroll
  for (int j = 0; j < 3; ++j) bb1[j] = B[1 + j];
#pragma unroll
  for (int j = 0; j < 5; ++j) bb2[j] = B[4 + j];

  float acc[51];
#pragma unroll
  for (int k = 0; k < 51; ++k) acc[k] = 0.0f;

  FOR_ALL_INSTR(DO_CONTRACT)
  FOR_ALL_INSTR(DO_EPI)
}

// ============================================================================

extern "C" void kernel_launch(void* const* d_in, const int* in_sizes, int n_in,
                              void* d_out, int out_size, void* d_ws,
                              size_t ws_size, hipStream_t stream) {
  static float h_coeff[615];
  static std::once_flag once;
  std::call_once(once, []() {
    nprng::build_coeff(h_coeff);
    // Pin so the captured H2D memcpy node DMAs directly (pageable source
    // would break graph capture). One-time host-side setup; per-call GPU
    // work is identical every call.
    (void)hipHostRegister(h_coeff, sizeof(h_coeff), hipHostRegisterDefault);
  });

  const float* in1 = (const float*)d_in[0];
  const float* in2 = (const float*)d_in[1];
  const float* wgt = (const float*)d_in[2];
  const int* esrc = (const int*)d_in[3];
  const int* edst = (const int*)d_in[4];
  float* out = (float*)d_out;
  float* ct = (float*)d_ws;

  int E = in_sizes[1] / 9;  // 100000

  hipMemcpyAsync(ct, h_coeff, sizeof(h_coeff), hipMemcpyHostToDevice, stream);
  hipMemsetAsync(out, 0, (size_t)out_size * sizeof(float), stream);

  int threads = E * 32;
  int blocks = (threads + 255) / 256;
  tp_kernel<<<blocks, 256, 0, stream>>>(in1, in2, wgt, esrc, edst, ct, out, E);
}

// Round 3
// 485.271 us; speedup vs baseline: 4.8914x; 4.8914x over previous
//
#include <hip/hip_runtime.h>
#include <cstdint>
#include <cmath>
#include <cstring>
#include <mutex>

// ============================================================================
// Host-side replication of numpy default_rng(42) -> CG coefficient table.
// (verified passing in R2: absmax 0.031)
// ============================================================================
namespace nprng {

typedef unsigned __int128 u128;

struct PCG64 {
  u128 state, inc;
  static inline u128 mult() {
    return ((u128)0x2360ED051FC65DA4ULL << 64) | 0x4385DF649FCCF645ULL;
  }
  inline void step() { state = state * mult() + inc; }
  inline uint64_t next() {
    step();
    uint64_t hi = (uint64_t)(state >> 64), lo = (uint64_t)state;
    uint64_t x = hi ^ lo;
    unsigned rot = (unsigned)(state >> 122);
    return (x >> rot) | (x << ((64u - rot) & 63u));
  }
  void srandom(u128 initstate, u128 initseq) {
    state = 0;
    inc = (initseq << 1) | 1;
    step();
    state += initstate;
    step();
  }
};

static void seed_sequence_42_raw(uint32_t st[8]) {
  uint32_t pool[4];
  uint32_t hash_const = 0x43b0d7e5u;  // INIT_A
  auto hashmix = [&hash_const](uint32_t v) -> uint32_t {
    v ^= hash_const;
    hash_const *= 0x931e8875u;  // MULT_A
    v *= hash_const;
    v ^= v >> 16;
    return v;
  };
  auto mix = [](uint32_t x, uint32_t y) -> uint32_t {
    uint32_t r = 0xca01f9ddu * x - 0x4973f715u * y;  // MULT_L*x - MULT_R*y
    r ^= r >> 16;
    return r;
  };
  pool[0] = hashmix(42u);
  for (int i = 1; i < 4; ++i) pool[i] = hashmix(0u);
  for (int s = 0; s < 4; ++s)
    for (int d = 0; d < 4; ++d)
      if (s != d) pool[d] = mix(pool[d], hashmix(pool[s]));
  uint32_t gen_const = 0x8b51f9ddu;  // INIT_B
  for (int i = 0; i < 8; ++i) {
    uint32_t v = pool[i & 3];
    v ^= gen_const;
    gen_const *= 0x58f38dedu;  // MULT_B
    v *= gen_const;
    v ^= v >> 16;
    st[i] = v;
  }
}

static inline double next_uniform(PCG64& g) {
  return (double)(g.next() >> 11) * (1.0 / 9007199254740992.0);
}

static void make_gen(PCG64& g) {
  uint32_t st[8];
  seed_sequence_42_raw(st);
  const double target = 0.7739560485559633;
  for (int pairing = 0; pairing < 2; ++pairing) {
    uint64_t s[4];
    for (int i = 0; i < 4; ++i)
      s[i] = pairing == 0
                 ? ((uint64_t)st[2 * i] | ((uint64_t)st[2 * i + 1] << 32))
                 : (((uint64_t)st[2 * i] << 32) | (uint64_t)st[2 * i + 1]);
    for (int so = 0; so < 2; ++so) {
      PCG64 t;
      if (so == 0)
        t.srandom(((u128)s[0] << 64) | s[1], ((u128)s[2] << 64) | s[3]);
      else
        t.srandom(((u128)s[1] << 64) | s[0], ((u128)s[3] << 64) | s[2]);
      PCG64 probe = t;
      if (fabs(next_uniform(probe) - target) < 1e-13) {
        g = t;
        return;
      }
    }
  }
  uint64_t s[4];
  for (int i = 0; i < 4; ++i)
    s[i] = (uint64_t)st[2 * i] | ((uint64_t)st[2 * i + 1] << 32);
  g.srandom(((u128)s[0] << 64) | s[1], ((u128)s[2] << 64) | s[3]);
}

struct Zig {
  double wi[256], fi[256];
  uint64_t ki[256];
};

static void build_zig(Zig& z) {
  const long double R = 3.6541528853610087963519472518L;
  const long double T52 = 4503599627370496.0L;  // 2^52
  long double f255 = expl(-0.5L * R * R);
  long double v =
      R * f255 +
      sqrtl(1.57079632679489661923132169163975144L) *
          erfcl(R / 1.41421356237309504880168872420969808L);
  long double x[256], fi[256];
  x[255] = R;
  fi[255] = f255;
  for (int i = 254; i >= 1; --i) {
    fi[i] = fi[i + 1] + v / x[i + 1];
    long double t = -2.0L * logl(fi[i]);
    x[i] = t > 0 ? sqrtl(t) : 0.0L;
  }
  x[0] = 0.0L;
  fi[0] = 1.0L;
  z.wi[0] = (double)(v / f255 / T52);
  z.fi[0] = 1.0;
  z.ki[0] = (uint64_t)((R * f255 / v) * T52);
  z.ki[1] = 0;
  for (int i = 1; i < 256; ++i) {
    z.wi[i] = (double)(x[i] / T52);
    z.fi[i] = (double)fi[i];
  }
  for (int i = 2; i < 256; ++i)
    z.ki[i] = (uint64_t)((x[i - 1] / x[i]) * T52);
}

static double next_normal(PCG64& g, const Zig& z) {
  const double ZR = 3.6541528853610087963519472518;
  const double ZIR = 0.27366123732975827203338247596;
  for (;;) {
    uint64_t r = g.next();
    int idx = (int)(r & 0xff);
    r >>= 8;
    int sign = (int)(r & 1);
    uint64_t rabs = (r >> 1) & 0x000fffffffffffffULL;
    double x = (double)rabs * z.wi[idx];
    if (sign) x = -x;
    if (rabs < z.ki[idx]) return x;
    if (idx == 0) {
      double xx, yy;
      do {
        xx = -ZIR * log1p(-next_uniform(g));
        yy = -log1p(-next_uniform(g));
      } while (yy + yy <= xx * xx);
      return ((rabs >> 8) & 1) ? -(ZR + xx) : (ZR + xx);
    } else {
      if ((z.fi[idx - 1] - z.fi[idx]) * next_uniform(g) + z.fi[idx] <
          exp(-0.5 * x * x))
        return x;
    }
  }
}

static const int kInstr[15][3] = {{0, 0, 0}, {0, 1, 1}, {0, 2, 2}, {1, 0, 1},
                                 {1, 1, 0}, {1, 1, 1}, {1, 1, 2}, {1, 2, 1},
                                 {1, 2, 2}, {2, 0, 2}, {2, 1, 1}, {2, 1, 2},
                                 {2, 2, 0}, {2, 2, 1}, {2, 2, 2}};
static const int kCOff[15] = {0,   1,   10,  35,  44,  53,  80, 125,
                              170, 245, 270, 315, 390, 415, 490};

static void build_coeff(float* coeff) {
  Zig z;
  build_zig(z);
  PCG64 g;
  make_gen(g);
  for (int t = 0; t < 15; ++t) {
    int d1 = 2 * kInstr[t][0] + 1;
    int d2 = 2 * kInstr[t][1] + 1;
    int d3 = 2 * kInstr[t][2] + 1;
    int n = d1 * d2 * d3;
    bool mask[125];
    bool any = false;
    for (int i = 0; i < n; ++i) {
      mask[i] = next_uniform(g) < 0.3;
      any |= mask[i];
    }
    if (!any) mask[0] = true;
    float pw = (float)(1.0 / sqrt((double)(d1 * d2)));
    for (int i = 0; i < n; ++i) {
      float v = (float)next_normal(g, z);
      coeff[kCOff[t] + i] = mask[i] ? v * pw : 0.0f;
    }
  }
}

}  // namespace nprng

// ============================================================================
// Path table macro: X(idx, l1, l2, l3, coeff_off, acc_off); out_off = 32*aoff.
// ============================================================================
#define FOR_ALL_INSTR(X)                                                   \
  X(0, 0, 0, 0, 0, 0)                                                      \
  X(1, 0, 1, 1, 1, 1)                                                      \
  X(2, 0, 2, 2, 10, 4)                                                     \
  X(3, 1, 0, 1, 35, 9)                                                     \
  X(4, 1, 1, 0, 44, 12)                                                    \
  X(5, 1, 1, 1, 53, 13)                                                    \
  X(6, 1, 1, 2, 80, 16)                                                    \
  X(7, 1, 2, 1, 125, 21)                                                   \
  X(8, 1, 2, 2, 170, 24)                                                   \
  X(9, 2, 0, 2, 245, 29)                                                   \
  X(10, 2, 1, 1, 270, 34)                                                  \
  X(11, 2, 1, 2, 315, 37)                                                  \
  X(12, 2, 2, 0, 390, 42)                                                  \
  X(13, 2, 2, 1, 415, 43)                                                  \
  X(14, 2, 2, 2, 490, 46)

// ============================================================================
// CSR build kernels (dst -> edge list). All scratch in d_ws.
// ============================================================================
__global__ void hist_kernel(const int* __restrict__ edst,
                            int* __restrict__ counts, int E) {
  int e = blockIdx.x * blockDim.x + threadIdx.x;
  if (e < E) atomicAdd(&counts[edst[e]], 1);
}

__global__ __launch_bounds__(1024) void scan_kernel(
    const int* __restrict__ counts, int* __restrict__ offsets, int n) {
  __shared__ int sh[1024];
  int t = threadIdx.x;
  int chunk = (n + 1023) >> 10;  // <=16
  int start = t * chunk;
  int local[16];
  int sum = 0;
  for (int i = 0; i < chunk; ++i) {
    int idx = start + i;
    int v = (idx < n) ? counts[idx] : 0;
    local[i] = sum;
    sum += v;
  }
  sh[t] = sum;
  __syncthreads();
  for (int off = 1; off < 1024; off <<= 1) {
    int v = (t >= off) ? sh[t - off] : 0;
    __syncthreads();
    sh[t] += v;
    __syncthreads();
  }
  int base = (t == 0) ? 0 : sh[t - 1];
  for (int i = 0; i < chunk; ++i) {
    int idx = start + i;
    if (idx < n) offsets[idx] = base + local[i];
  }
  if (t == 1023) offsets[n] = sh[1023];
}

__global__ void fill_kernel(const int* __restrict__ edst,
                            const int* __restrict__ offsets,
                            int* __restrict__ cursor, int* __restrict__ csr,
                            int E) {
  int e = blockIdx.x * blockDim.x + threadIdx.x;
  if (e >= E) return;
  int d = edst[e];
  int pos = atomicAdd(&cursor[d], 1);
  csr[offsets[d] + pos] = e;
}

// ============================================================================
// Main compute: 1 thread per (node, u). Registers-only accumulation over the
// node's incoming edges; single coalesced write of 51 outputs. No atomics.
// ============================================================================
template <int D1, int D2, int D3, int COFF, int AOFF>
__device__ __forceinline__ void contract_w(const float* __restrict__ ct,
                                           const float (&a)[D1],
                                           const float (&b)[D2], float w,
                                           float (&acc)[51]) {
  float tmp[D3];
#pragma unroll
  for (int k = 0; k < D3; ++k) tmp[k] = 0.0f;
#pragma unroll
  for (int i = 0; i < D1; ++i)
#pragma unroll
    for (int j = 0; j < D2; ++j) {
      float ab = a[i] * b[j];
#pragma unroll
      for (int k = 0; k < D3; ++k)
        tmp[k] = fmaf(ab, ct[COFF + (i * D2 + j) * D3 + k], tmp[k]);
    }
#pragma unroll
  for (int k = 0; k < D3; ++k)
    acc[AOFF + k] = fmaf(w, tmp[k], acc[AOFF + k]);
}

#define DO_CONTRACT_W(idx, l1, l2, l3, coff, aoff)                      \
  contract_w<2 * (l1) + 1, 2 * (l2) + 1, 2 * (l3) + 1, coff, aoff>(     \
      ct, aa##l1, bb##l2, ww[idx], acc);

#define DO_STORE(idx, l1, l2, l3, coff, aoff)                           \
  _Pragma("unroll") for (int k = 0; k < 2 * (l3) + 1; ++k)              \
      O[(aoff) * 32 + u * (2 * (l3) + 1) + k] = acc[(aoff) + k];

__global__ __launch_bounds__(256) void tp_node_kernel(
    const float* __restrict__ in1, const float* __restrict__ in2,
    const float* __restrict__ weight, const int* __restrict__ esrc,
    const float* __restrict__ ct, const int* __restrict__ offsets,
    const int* __restrict__ csr, float* __restrict__ out, int N) {
  int t = blockIdx.x * blockDim.x + threadIdx.x;
  int n = t >> 5;
  if (n >= N) return;
  int u = t & 31;
  int beg = offsets[n];
  int end = offsets[n + 1];

  float acc[51];
#pragma unroll
  for (int k = 0; k < 51; ++k) acc[k] = 0.0f;

  for (int ii = beg; ii < end; ++ii) {
    int e = csr[ii];
    int s = esrc[e];
    const float* __restrict__ A = in1 + (size_t)s * 288;
    const float* __restrict__ B = in2 + (size_t)e * 9;
    const float* __restrict__ W = weight + (size_t)e * 480 + u;

    float aa0[1], aa1[3], aa2[5], bb0[1], bb1[3], bb2[5];
    aa0[0] = A[u];
#pragma unroll
    for (int i = 0; i < 3; ++i) aa1[i] = A[32 + u * 3 + i];
#pragma unroll
    for (int i = 0; i < 5; ++i) aa2[i] = A[128 + u * 5 + i];
    bb0[0] = B[0];
#pragma unroll
    for (int j = 0; j < 3; ++j) bb1[j] = B[1 + j];
#pragma unroll
    for (int j = 0; j < 5; ++j) bb2[j] = B[4 + j];

    float ww[15];
#pragma unroll
    for (int p = 0; p < 15; ++p) ww[p] = W[p * 32];

    FOR_ALL_INSTR(DO_CONTRACT_W)
  }

  float* __restrict__ O = out + (size_t)n * 1632;
  FOR_ALL_INSTR(DO_STORE)
}

// ============================================================================
// Fallback (R2 atomic kernel) if ws_size is too small for CSR scratch.
// ============================================================================
template <int D1, int D2, int D3, int COFF, int AOFF>
__device__ __forceinline__ void contract(const float* __restrict__ ct,
                                         const float (&a)[D1],
                                         const float (&b)[D2],
                                         float (&acc)[51]) {
#pragma unroll
  for (int i = 0; i < D1; ++i)
#pragma unroll
    for (int j = 0; j < D2; ++j) {
      float ab = a[i] * b[j];
#pragma unroll
      for (int k = 0; k < D3; ++k)
        acc[AOFF + k] =
            fmaf(ab, ct[COFF + (i * D2 + j) * D3 + k], acc[AOFF + k]);
    }
}

#define DO_CONTRACT(idx, l1, l2, l3, coff, aoff)                       \
  contract<2 * (l1) + 1, 2 * (l2) + 1, 2 * (l3) + 1, coff, aoff>(      \
      ct, aa##l1, bb##l2, acc);

#define DO_EPI(idx, l1, l2, l3, coff, aoff)                            \
  {                                                                    \
    float wv = W[(idx) * 32];                                          \
    _Pragma("unroll") for (int k = 0; k < 2 * (l3) + 1; ++k)           \
        atomicAdd(O + ((aoff) * 32 + u * (2 * (l3) + 1) + k),          \
                  acc[(aoff) + k] * wv);                               \
  }

__global__ __launch_bounds__(256) void tp_kernel(
    const float* __restrict__ in1, const float* __restrict__ in2,
    const float* __restrict__ weight, const int* __restrict__ esrc,
    const int* __restrict__ edst, const float* __restrict__ ct,
    float* __restrict__ out, int E) {
  int t = blockIdx.x * blockDim.x + threadIdx.x;
  int e = t >> 5;
  if (e >= E) return;
  int u = t & 31;
  int s = esrc[e];
  int d = edst[e];
  const float* __restrict__ A = in1 + (size_t)s * 288;
  const float* __restrict__ B = in2 + (size_t)e * 9;
  const float* __restrict__ W = weight + (size_t)e * 480 + u;
  float* __restrict__ O = out + (size_t)d * 1632;

  float aa0[1], aa1[3], aa2[5], bb0[1], bb1[3], bb2[5];
  aa0[0] = A[u];
#pragma unroll
  for (int i = 0; i < 3; ++i) aa1[i] = A[32 + u * 3 + i];
#pragma unroll
  for (int i = 0; i < 5; ++i) aa2[i] = A[128 + u * 5 + i];
  bb0[0] = B[0];
#pragma unroll
  for (int j = 0; j < 3; ++j) bb1[j] = B[1 + j];
#pragma unroll
  for (int j = 0; j < 5; ++j) bb2[j] = B[4 + j];

  float acc[51];
#pragma unroll
  for (int k = 0; k < 51; ++k) acc[k] = 0.0f;

  FOR_ALL_INSTR(DO_CONTRACT)
  FOR_ALL_INSTR(DO_EPI)
}

// ============================================================================

extern "C" void kernel_launch(void* const* d_in, const int* in_sizes, int n_in,
                              void* d_out, int out_size, void* d_ws,
                              size_t ws_size, hipStream_t stream) {
  static float h_coeff[615];
  static std::once_flag once;
  std::call_once(once, []() {
    nprng::build_coeff(h_coeff);
    (void)hipHostRegister(h_coeff, sizeof(h_coeff), hipHostRegisterDefault);
  });

  const float* in1 = (const float*)d_in[0];
  const float* in2 = (const float*)d_in[1];
  const float* wgt = (const float*)d_in[2];
  const int* esrc = (const int*)d_in[3];
  const int* edst = (const int*)d_in[4];
  float* out = (float*)d_out;

  int N = in_sizes[0] / 288;  // 10000
  int E = in_sizes[1] / 9;    // 100000

  // ws layout (ints): [0,640) ct | [640, 640+N) counts | [640+N, 640+2N)
  // cursor | [640+2N, 640+3N+1) offsets | [align16 up, +E) csr
  int* ws = (int*)d_ws;
  const int CT_OFF = 0;
  const int CNT_OFF = 640;
  const int CUR_OFF = CNT_OFF + N;
  const int OFF_OFF = CUR_OFF + N;
  int csr_off = OFF_OFF + N + 1;
  csr_off = (csr_off + 3) & ~3;
  size_t needed = (size_t)(csr_off + E) * 4;

  float* ct = (float*)(ws + CT_OFF);
  hipMemcpyAsync(ct, h_coeff, sizeof(h_coeff), hipMemcpyHostToDevice, stream);

  if (ws_size >= needed) {
    int* counts = ws + CNT_OFF;
    int* cursor = ws + CUR_OFF;
    int* offsets = ws + OFF_OFF;
    int* csr = ws + csr_off;

    // zero counts + cursor (adjacent regions, one memset)
    hipMemsetAsync(counts, 0, (size_t)(2 * N) * 4, stream);
    hist_kernel<<<(E + 255) / 256, 256, 0, stream>>>(edst, counts, E);
    scan_kernel<<<1, 1024, 0, stream>>>(counts, offsets, N);
    fill_kernel<<<(E + 255) / 256, 256, 0, stream>>>(edst, offsets, cursor,
                                                     csr, E);
    int threads = N * 32;
    tp_node_kernel<<<(threads + 255) / 256, 256, 0, stream>>>(
        in1, in2, wgt, esrc, ct, offsets, csr, out, N);
  } else {
    // Fallback: R2 atomic path.
    hipMemsetAsync(out, 0, (size_t)out_size * sizeof(float), stream);
    int threads = E * 32;
    tp_kernel<<<(threads + 255) / 256, 256, 0, stream>>>(in1, in2, wgt, esrc,
                                                         edst, ct, out, E);
  }
}

// Round 4
// 439.057 us; speedup vs baseline: 5.4063x; 1.1053x over previous
//
#include <hip/hip_runtime.h>
#include <cstdint>
#include <cmath>
#include <cstring>
#include <mutex>

// ============================================================================
// Host-side replication of numpy default_rng(42) -> CG coefficient table.
// (verified passing in R2/R3: absmax 0.031)
// ============================================================================
namespace nprng {

typedef unsigned __int128 u128;

struct PCG64 {
  u128 state, inc;
  static inline u128 mult() {
    return ((u128)0x2360ED051FC65DA4ULL << 64) | 0x4385DF649FCCF645ULL;
  }
  inline void step() { state = state * mult() + inc; }
  inline uint64_t next() {
    step();
    uint64_t hi = (uint64_t)(state >> 64), lo = (uint64_t)state;
    uint64_t x = hi ^ lo;
    unsigned rot = (unsigned)(state >> 122);
    return (x >> rot) | (x << ((64u - rot) & 63u));
  }
  void srandom(u128 initstate, u128 initseq) {
    state = 0;
    inc = (initseq << 1) | 1;
    step();
    state += initstate;
    step();
  }
};

static void seed_sequence_42_raw(uint32_t st[8]) {
  uint32_t pool[4];
  uint32_t hash_const = 0x43b0d7e5u;  // INIT_A
  auto hashmix = [&hash_const](uint32_t v) -> uint32_t {
    v ^= hash_const;
    hash_const *= 0x931e8875u;  // MULT_A
    v *= hash_const;
    v ^= v >> 16;
    return v;
  };
  auto mix = [](uint32_t x, uint32_t y) -> uint32_t {
    uint32_t r = 0xca01f9ddu * x - 0x4973f715u * y;  // MULT_L*x - MULT_R*y
    r ^= r >> 16;
    return r;
  };
  pool[0] = hashmix(42u);
  for (int i = 1; i < 4; ++i) pool[i] = hashmix(0u);
  for (int s = 0; s < 4; ++s)
    for (int d = 0; d < 4; ++d)
      if (s != d) pool[d] = mix(pool[d], hashmix(pool[s]));
  uint32_t gen_const = 0x8b51f9ddu;  // INIT_B
  for (int i = 0; i < 8; ++i) {
    uint32_t v = pool[i & 3];
    v ^= gen_const;
    gen_const *= 0x58f38dedu;  // MULT_B
    v *= gen_const;
    v ^= v >> 16;
    st[i] = v;
  }
}

static inline double next_uniform(PCG64& g) {
  return (double)(g.next() >> 11) * (1.0 / 9007199254740992.0);
}

static void make_gen(PCG64& g) {
  uint32_t st[8];
  seed_sequence_42_raw(st);
  const double target = 0.7739560485559633;
  for (int pairing = 0; pairing < 2; ++pairing) {
    uint64_t s[4];
    for (int i = 0; i < 4; ++i)
      s[i] = pairing == 0
                 ? ((uint64_t)st[2 * i] | ((uint64_t)st[2 * i + 1] << 32))
                 : (((uint64_t)st[2 * i] << 32) | (uint64_t)st[2 * i + 1]);
    for (int so = 0; so < 2; ++so) {
      PCG64 t;
      if (so == 0)
        t.srandom(((u128)s[0] << 64) | s[1], ((u128)s[2] << 64) | s[3]);
      else
        t.srandom(((u128)s[1] << 64) | s[0], ((u128)s[3] << 64) | s[2]);
      PCG64 probe = t;
      if (fabs(next_uniform(probe) - target) < 1e-13) {
        g = t;
        return;
      }
    }
  }
  uint64_t s[4];
  for (int i = 0; i < 4; ++i)
    s[i] = (uint64_t)st[2 * i] | ((uint64_t)st[2 * i + 1] << 32);
  g.srandom(((u128)s[0] << 64) | s[1], ((u128)s[2] << 64) | s[3]);
}

struct Zig {
  double wi[256], fi[256];
  uint64_t ki[256];
};

static void build_zig(Zig& z) {
  const long double R = 3.6541528853610087963519472518L;
  const long double T52 = 4503599627370496.0L;  // 2^52
  long double f255 = expl(-0.5L * R * R);
  long double v =
      R * f255 +
      sqrtl(1.57079632679489661923132169163975144L) *
          erfcl(R / 1.41421356237309504880168872420969808L);
  long double x[256], fi[256];
  x[255] = R;
  fi[255] = f255;
  for (int i = 254; i >= 1; --i) {
    fi[i] = fi[i + 1] + v / x[i + 1];
    long double t = -2.0L * logl(fi[i]);
    x[i] = t > 0 ? sqrtl(t) : 0.0L;
  }
  x[0] = 0.0L;
  fi[0] = 1.0L;
  z.wi[0] = (double)(v / f255 / T52);
  z.fi[0] = 1.0;
  z.ki[0] = (uint64_t)((R * f255 / v) * T52);
  z.ki[1] = 0;
  for (int i = 1; i < 256; ++i) {
    z.wi[i] = (double)(x[i] / T52);
    z.fi[i] = (double)fi[i];
  }
  for (int i = 2; i < 256; ++i)
    z.ki[i] = (uint64_t)((x[i - 1] / x[i]) * T52);
}

static double next_normal(PCG64& g, const Zig& z) {
  const double ZR = 3.6541528853610087963519472518;
  const double ZIR = 0.27366123732975827203338247596;
  for (;;) {
    uint64_t r = g.next();
    int idx = (int)(r & 0xff);
    r >>= 8;
    int sign = (int)(r & 1);
    uint64_t rabs = (r >> 1) & 0x000fffffffffffffULL;
    double x = (double)rabs * z.wi[idx];
    if (sign) x = -x;
    if (rabs < z.ki[idx]) return x;
    if (idx == 0) {
      double xx, yy;
      do {
        xx = -ZIR * log1p(-next_uniform(g));
        yy = -log1p(-next_uniform(g));
      } while (yy + yy <= xx * xx);
      return ((rabs >> 8) & 1) ? -(ZR + xx) : (ZR + xx);
    } else {
      if ((z.fi[idx - 1] - z.fi[idx]) * next_uniform(g) + z.fi[idx] <
          exp(-0.5 * x * x))
        return x;
    }
  }
}

static const int kInstr[15][3] = {{0, 0, 0}, {0, 1, 1}, {0, 2, 2}, {1, 0, 1},
                                 {1, 1, 0}, {1, 1, 1}, {1, 1, 2}, {1, 2, 1},
                                 {1, 2, 2}, {2, 0, 2}, {2, 1, 1}, {2, 1, 2},
                                 {2, 2, 0}, {2, 2, 1}, {2, 2, 2}};
static const int kCOff[15] = {0,   1,   10,  35,  44,  53,  80, 125,
                              170, 245, 270, 315, 390, 415, 490};

static void build_coeff(float* coeff) {
  Zig z;
  build_zig(z);
  PCG64 g;
  make_gen(g);
  for (int t = 0; t < 15; ++t) {
    int d1 = 2 * kInstr[t][0] + 1;
    int d2 = 2 * kInstr[t][1] + 1;
    int d3 = 2 * kInstr[t][2] + 1;
    int n = d1 * d2 * d3;
    bool mask[125];
    bool any = false;
    for (int i = 0; i < n; ++i) {
      mask[i] = next_uniform(g) < 0.3;
      any |= mask[i];
    }
    if (!any) mask[0] = true;
    float pw = (float)(1.0 / sqrt((double)(d1 * d2)));
    for (int i = 0; i < n; ++i) {
      float v = (float)next_normal(g, z);
      coeff[kCOff[t] + i] = mask[i] ? v * pw : 0.0f;
    }
  }
}

}  // namespace nprng

// ============================================================================
// Path tables. X(idx, l1, l2, l3, coeff_off, acc_off); out_off = 32*aoff.
// Split into two FLOP-balanced halves with disjoint weight cols + outputs:
//   A = {0,1,6,8,11,14}  cost ~422      B = {2,3,4,5,7,9,10,12,13} cost ~423
// ============================================================================
#define FOR_ALL_INSTR(X)                                                   \
  X(0, 0, 0, 0, 0, 0)                                                      \
  X(1, 0, 1, 1, 1, 1)                                                      \
  X(2, 0, 2, 2, 10, 4)                                                     \
  X(3, 1, 0, 1, 35, 9)                                                     \
  X(4, 1, 1, 0, 44, 12)                                                    \
  X(5, 1, 1, 1, 53, 13)                                                    \
  X(6, 1, 1, 2, 80, 16)                                                    \
  X(7, 1, 2, 1, 125, 21)                                                   \
  X(8, 1, 2, 2, 170, 24)                                                   \
  X(9, 2, 0, 2, 245, 29)                                                   \
  X(10, 2, 1, 1, 270, 34)                                                  \
  X(11, 2, 1, 2, 315, 37)                                                  \
  X(12, 2, 2, 0, 390, 42)                                                  \
  X(13, 2, 2, 1, 415, 43)                                                  \
  X(14, 2, 2, 2, 490, 46)

#define FOR_INSTR_A(X)                                                     \
  X(0, 0, 0, 0, 0, 0)                                                      \
  X(1, 0, 1, 1, 1, 1)                                                      \
  X(6, 1, 1, 2, 80, 16)                                                    \
  X(8, 1, 2, 2, 170, 24)                                                   \
  X(11, 2, 1, 2, 315, 37)                                                  \
  X(14, 2, 2, 2, 490, 46)

#define FOR_INSTR_B(X)                                                     \
  X(2, 0, 2, 2, 10, 4)                                                     \
  X(3, 1, 0, 1, 35, 9)                                                     \
  X(4, 1, 1, 0, 44, 12)                                                    \
  X(5, 1, 1, 1, 53, 13)                                                    \
  X(7, 1, 2, 1, 125, 21)                                                   \
  X(9, 2, 0, 2, 245, 29)                                                   \
  X(10, 2, 1, 1, 270, 34)                                                  \
  X(12, 2, 2, 0, 390, 42)                                                  \
  X(13, 2, 2, 1, 415, 43)

// ============================================================================
// CSR build kernels (dst -> edge list). All scratch in d_ws.
// ============================================================================
__global__ void hist_kernel(const int* __restrict__ edst,
                            int* __restrict__ counts, int E) {
  int e = blockIdx.x * blockDim.x + threadIdx.x;
  if (e < E) atomicAdd(&counts[edst[e]], 1);
}

__global__ __launch_bounds__(1024) void scan_kernel(
    const int* __restrict__ counts, int* __restrict__ offsets, int n) {
  __shared__ int sh[1024];
  int t = threadIdx.x;
  int chunk = (n + 1023) >> 10;  // <=16
  int start = t * chunk;
  int local[16];
  int sum = 0;
  for (int i = 0; i < chunk; ++i) {
    int idx = start + i;
    int v = (idx < n) ? counts[idx] : 0;
    local[i] = sum;
    sum += v;
  }
  sh[t] = sum;
  __syncthreads();
  for (int off = 1; off < 1024; off <<= 1) {
    int v = (t >= off) ? sh[t - off] : 0;
    __syncthreads();
    sh[t] += v;
    __syncthreads();
  }
  int base = (t == 0) ? 0 : sh[t - 1];
  for (int i = 0; i < chunk; ++i) {
    int idx = start + i;
    if (idx < n) offsets[idx] = base + local[i];
  }
  if (t == 1023) offsets[n] = sh[1023];
}

__global__ void fill_kernel(const int* __restrict__ edst,
                            const int* __restrict__ offsets,
                            int* __restrict__ cursor, int* __restrict__ csr,
                            int E) {
  int e = blockIdx.x * blockDim.x + threadIdx.x;
  if (e >= E) return;
  int d = edst[e];
  int pos = atomicAdd(&cursor[d], 1);
  csr[offsets[d] + pos] = e;
}

// ============================================================================
// Main compute: thread = (node, u, es, ps).
//   u  = t&31      : mul channel
//   es = (t>>5)&1  : edge parity (in-wave, reduced via shfl_xor 32)
//   ps = (t>>6)&1  : path half (separate wave; disjoint weights & outputs)
//   n  = t>>7
// No atomics, no LDS; single coalesced store of each output element.
// ============================================================================
template <int D1, int D2, int D3, int COFF, int AOFF, int NACC>
__device__ __forceinline__ void contract_w(const float* __restrict__ ct,
                                           const float (&a)[D1],
                                           const float (&b)[D2], float w,
                                           float (&acc)[NACC]) {
  float tmp[D3];
#pragma unroll
  for (int k = 0; k < D3; ++k) tmp[k] = 0.0f;
#pragma unroll
  for (int i = 0; i < D1; ++i)
#pragma unroll
    for (int j = 0; j < D2; ++j) {
      float ab = a[i] * b[j];
#pragma unroll
      for (int k = 0; k < D3; ++k)
        tmp[k] = fmaf(ab, ct[COFF + (i * D2 + j) * D3 + k], tmp[k]);
    }
#pragma unroll
  for (int k = 0; k < D3; ++k)
    acc[AOFF + k] = fmaf(w, tmp[k], acc[AOFF + k]);
}

#define DO_CONTRACT_W(idx, l1, l2, l3, coff, aoff)                          \
  contract_w<2 * (l1) + 1, 2 * (l2) + 1, 2 * (l3) + 1, coff, aoff, 51>(     \
      ct, aa##l1, bb##l2, ww[idx], acc);

#define DO_REDUCE(idx, l1, l2, l3, coff, aoff)                              \
  _Pragma("unroll") for (int k = 0; k < 2 * (l3) + 1; ++k)                  \
      acc[(aoff) + k] += __shfl_xor(acc[(aoff) + k], 32, 64);

#define DO_STORE(idx, l1, l2, l3, coff, aoff)                               \
  _Pragma("unroll") for (int k = 0; k < 2 * (l3) + 1; ++k)                  \
      O[(aoff) * 32 + u * (2 * (l3) + 1) + k] = acc[(aoff) + k];

#define DO_LOADW(idx, l1, l2, l3, coff, aoff) ww[idx] = W[(idx) * 32];

#define EDGE_BODY(INSTR_LIST)                                               \
  for (int ii = beg + es; ii < end; ii += 2) {                              \
    int e = csr[ii];                                                        \
    int s = esrc[e];                                                        \
    const float* __restrict__ A = in1 + (size_t)s * 288;                    \
    const float* __restrict__ B = in2 + (size_t)e * 9;                      \
    const float* __restrict__ W = weight + (size_t)e * 480 + u;             \
    float aa0[1], aa1[3], aa2[5], bb0[1], bb1[3], bb2[5];                   \
    aa0[0] = A[u];                                                          \
    _Pragma("unroll") for (int i = 0; i < 3; ++i) aa1[i] = A[32 + u * 3 + i]; \
    _Pragma("unroll") for (int i = 0; i < 5; ++i) aa2[i] = A[128 + u * 5 + i]; \
    bb0[0] = B[0];                                                          \
    _Pragma("unroll") for (int j = 0; j < 3; ++j) bb1[j] = B[1 + j];        \
    _Pragma("unroll") for (int j = 0; j < 5; ++j) bb2[j] = B[4 + j];        \
    float ww[15];                                                           \
    INSTR_LIST(DO_LOADW)                                                    \
    INSTR_LIST(DO_CONTRACT_W)                                               \
  }

__global__ __launch_bounds__(256) void tp_node_kernel(
    const float* __restrict__ in1, const float* __restrict__ in2,
    const float* __restrict__ weight, const int* __restrict__ esrc,
    const float* __restrict__ ct, const int* __restrict__ offsets,
    const int* __restrict__ csr, float* __restrict__ out, int N) {
  int t = blockIdx.x * blockDim.x + threadIdx.x;
  int u = t & 31;
  int es = (t >> 5) & 1;
  int ps = (t >> 6) & 1;
  int n = t >> 7;
  if (n >= N) return;
  int beg = offsets[n];
  int end = offsets[n + 1];

  float acc[51];
#pragma unroll
  for (int k = 0; k < 51; ++k) acc[k] = 0.0f;

  if (ps == 0) {
    EDGE_BODY(FOR_INSTR_A)
    FOR_INSTR_A(DO_REDUCE)
    if (es == 0) {
      float* __restrict__ O = out + (size_t)n * 1632;
      FOR_INSTR_A(DO_STORE)
    }
  } else {
    EDGE_BODY(FOR_INSTR_B)
    FOR_INSTR_B(DO_REDUCE)
    if (es == 0) {
      float* __restrict__ O = out + (size_t)n * 1632;
      FOR_INSTR_B(DO_STORE)
    }
  }
}

// ============================================================================
// Fallback (R2 atomic kernel) if ws_size is too small for CSR scratch.
// ============================================================================
template <int D1, int D2, int D3, int COFF, int AOFF>
__device__ __forceinline__ void contract(const float* __restrict__ ct,
                                         const float (&a)[D1],
                                         const float (&b)[D2],
                                         float (&acc)[51]) {
#pragma unroll
  for (int i = 0; i < D1; ++i)
#pragma unroll
    for (int j = 0; j < D2; ++j) {
      float ab = a[i] * b[j];
#pragma unroll
      for (int k = 0; k < D3; ++k)
        acc[AOFF + k] =
            fmaf(ab, ct[COFF + (i * D2 + j) * D3 + k], acc[AOFF + k]);
    }
}

#define DO_CONTRACT(idx, l1, l2, l3, coff, aoff)                       \
  contract<2 * (l1) + 1, 2 * (l2) + 1, 2 * (l3) + 1, coff, aoff>(      \
      ct, aa##l1, bb##l2, acc);

#define DO_EPI(idx, l1, l2, l3, coff, aoff)                            \
  {                                                                    \
    float wv = W[(idx) * 32];                                          \
    _Pragma("unroll") for (int k = 0; k < 2 * (l3) + 1; ++k)           \
        atomicAdd(O + ((aoff) * 32 + u * (2 * (l3) + 1) + k),          \
                  acc[(aoff) + k] * wv);                               \
  }

__global__ __launch_bounds__(256) void tp_kernel(
    const float* __restrict__ in1, const float* __restrict__ in2,
    const float* __restrict__ weight, const int* __restrict__ esrc,
    const int* __restrict__ edst, const float* __restrict__ ct,
    float* __restrict__ out, int E) {
  int t = blockIdx.x * blockDim.x + threadIdx.x;
  int e = t >> 5;
  if (e >= E) return;
  int u = t & 31;
  int s = esrc[e];
  int d = edst[e];
  const float* __restrict__ A = in1 + (size_t)s * 288;
  const float* __restrict__ B = in2 + (size_t)e * 9;
  const float* __restrict__ W = weight + (size_t)e * 480 + u;
  float* __restrict__ O = out + (size_t)d * 1632;

  float aa0[1], aa1[3], aa2[5], bb0[1], bb1[3], bb2[5];
  aa0[0] = A[u];
#pragma unroll
  for (int i = 0; i < 3; ++i) aa1[i] = A[32 + u * 3 + i];
#pragma unroll
  for (int i = 0; i < 5; ++i) aa2[i] = A[128 + u * 5 + i];
  bb0[0] = B[0];
#pragma unroll
  for (int j = 0; j < 3; ++j) bb1[j] = B[1 + j];
#pragma unroll
  for (int j = 0; j < 5; ++j) bb2[j] = B[4 + j];

  float acc[51];
#pragma unroll
  for (int k = 0; k < 51; ++k) acc[k] = 0.0f;

  FOR_ALL_INSTR(DO_CONTRACT)
  FOR_ALL_INSTR(DO_EPI)
}

// ============================================================================

extern "C" void kernel_launch(void* const* d_in, const int* in_sizes, int n_in,
                              void* d_out, int out_size, void* d_ws,
                              size_t ws_size, hipStream_t stream) {
  static float h_coeff[615];
  static std::once_flag once;
  std::call_once(once, []() {
    nprng::build_coeff(h_coeff);
    (void)hipHostRegister(h_coeff, sizeof(h_coeff), hipHostRegisterDefault);
  });

  const float* in1 = (const float*)d_in[0];
  const float* in2 = (const float*)d_in[1];
  const float* wgt = (const float*)d_in[2];
  const int* esrc = (const int*)d_in[3];
  const int* edst = (const int*)d_in[4];
  float* out = (float*)d_out;

  int N = in_sizes[0] / 288;  // 10000
  int E = in_sizes[1] / 9;    // 100000

  // ws layout (ints): [0,640) ct | [640, 640+N) counts | [640+N, 640+2N)
  // cursor | [640+2N, 640+3N+1) offsets | [align16 up, +E) csr
  int* ws = (int*)d_ws;
  const int CT_OFF = 0;
  const int CNT_OFF = 640;
  const int CUR_OFF = CNT_OFF + N;
  const int OFF_OFF = CUR_OFF + N;
  int csr_off = OFF_OFF + N + 1;
  csr_off = (csr_off + 3) & ~3;
  size_t needed = (size_t)(csr_off + E) * 4;

  float* ct = (float*)(ws + CT_OFF);
  hipMemcpyAsync(ct, h_coeff, sizeof(h_coeff), hipMemcpyHostToDevice, stream);

  if (ws_size >= needed) {
    int* counts = ws + CNT_OFF;
    int* cursor = ws + CUR_OFF;
    int* offsets = ws + OFF_OFF;
    int* csr = ws + csr_off;

    hipMemsetAsync(counts, 0, (size_t)(2 * N) * 4, stream);
    hist_kernel<<<(E + 255) / 256, 256, 0, stream>>>(edst, counts, E);
    scan_kernel<<<1, 1024, 0, stream>>>(counts, offsets, N);
    fill_kernel<<<(E + 255) / 256, 256, 0, stream>>>(edst, offsets, cursor,
                                                     csr, E);
    long long threads = (long long)N * 128;
    int blocks = (int)((threads + 255) / 256);
    tp_node_kernel<<<blocks, 256, 0, stream>>>(in1, in2, wgt, esrc, ct,
                                               offsets, csr, out, N);
  } else {
    // Fallback: R2 atomic path.
    hipMemsetAsync(out, 0, (size_t)out_size * sizeof(float), stream);
    int threads = E * 32;
    tp_kernel<<<(threads + 255) / 256, 256, 0, stream>>>(in1, in2, wgt, esrc,
                                                         edst, ct, out, E);
  }
}